// Round 3
// baseline (1068.795 us; speedup 1.0000x reference)
//
#include <hip/hip_runtime.h>

// FeatureGradFetcher: B=2 V=5 C=16 H=512 W=640 N=131072
// out = concat(f (B,V,C,N), f_grad (B,V,C,N,2)) flat, float32.
//
// R4 changes vs R3:
//  1) Pipeline per 2-bv chunk: transpose(2 planes) then gather(2 planes),
//     10x each. Gather working set = 42MB << 256MB L3 and the planes are
//     L3-resident from the transpose's own (cached) writes -> tap misses
//     should be served by L3, not HBM. (R3 evidence: monolithic gather
//     fetched 2.19GB from HBM = 10x compulsory; all 210MB of fmt live at
//     once ~ L3 capacity, so it thrashed.)
//  2) transpose loads widened to dwordx4 (1KB/wave vs 256B/wave scalar) and
//     nt-load hint dropped (R3: fixing stores alone moved transpose only
//     377->345us, so loads were the limiter).
//  3) gather output stores stay nontemporal (keeps the 252MB write stream
//     out of L3 so it can hold the fmt planes).

namespace {
constexpr int Bc = 2, Vc = 5, Cc = 16, Hc = 512, Wc = 640;
constexpr int Nc = 131072;
constexpr int BVc = Bc * Vc;
constexpr int HWc = Hc * Wc;
constexpr size_t FMT_BYTES = (size_t)BVc * HWc * Cc * sizeof(float);  // 209,715,200
constexpr int BV_CHUNK = 2;  // planes per transpose+gather pipeline stage

typedef float f32x2 __attribute__((ext_vector_type(2)));

__device__ __forceinline__ void axis_decomp(float t, int limit,
                                            int& i0, int& i1,
                                            float& w0, float& w1) {
    float f0 = floorf(t);
    float fr = t - f0;
    float f1 = f0 + 1.0f;
    float lim = (float)(limit - 1);
    w0 = (1.0f - fr) * ((f0 >= 0.0f && f0 <= lim) ? 1.0f : 0.0f);
    w1 = fr * ((f1 >= 0.0f && f1 <= lim) ? 1.0f : 0.0f);
    int i = (int)f0;
    i0 = min(max(i, 0), limit - 1);
    i1 = min(max(i + 1, 0), limit - 1);
}

// ---- fm (BV,C,H,W) -> fmt (BV,H,W,C), for BV_CHUNK planes at bv_base ----
// Block: 256 threads, 256 pixels, 16 channels, 16KB LDS.
// Loads: 4x dwordx4/thread; each wave-load covers 64 consecutive float4
// (1KB contiguous) from one channel row.  Stores: 4x dwordx4/thread, wave
// covers 1KB contiguous of fmt.  LDS: write ~2-way quarter-wave (free),
// read 4-way on 16KB traffic (negligible).
__global__ __launch_bounds__(256) void transpose_kernel(
    const float* __restrict__ fm, float* __restrict__ fmt, int bv_base) {
    __shared__ float lds[16 * 256];
    const int blocks_per_bv = HWc / 256;  // 1280
    const int bv = bv_base + (int)blockIdx.x / blocks_per_bv;
    const int pix0 = ((int)blockIdx.x % blocks_per_bv) * 256;
    const int t = (int)threadIdx.x;
#pragma unroll
    for (int i = 0; i < 4; ++i) {
        const int l = i * 256 + t;   // float4 slot 0..1023
        const int c = l >> 6;        // channel 0..15
        const int m = l & 63;        // float4 within the 256-px channel row
        const float4 v = *reinterpret_cast<const float4*>(
            fm + (size_t)(bv * 16 + c) * HWc + pix0 + 4 * m);
        *reinterpret_cast<float4*>(&lds[c * 256 + 4 * m]) = v;
    }
    __syncthreads();
    float4* dst = reinterpret_cast<float4*>(fmt + (size_t)(bv * HWc + pix0) * 16);
#pragma unroll
    for (int j = 0; j < 4; ++j) {
        const int q = j * 256 + t;  // float4 index in the 16KB block region
        const int p = q >> 2;       // pixel 0..255
        const int k = q & 3;        // float4 within pixel (channel group)
        float4 v;
        v.x = lds[(4 * k + 0) * 256 + p];
        v.y = lds[(4 * k + 1) * 256 + p];
        v.z = lds[(4 * k + 2) * 256 + p];
        v.w = lds[(4 * k + 3) * 256 + p];
        dst[q] = v;  // cached: gather for this chunk reads it from L3
    }
}

// ---- gather: one thread per (bv, n), all 16 channels; BV_CHUNK planes ----
__global__ __launch_bounds__(256) void gather_kernel(
    const float* __restrict__ fmt,   // (BV, H, W, C)
    const float* __restrict__ pts,   // (B, 3, N)
    const float* __restrict__ Kmat,  // (BV, 3, 3)
    const float* __restrict__ Emat,  // (BV, 3, 4)
    float* __restrict__ out_f,       // (BV, C, N)
    float* __restrict__ out_g,       // (BV, C, N, 2)
    int bv_base)
{
    const int n  = (((int)blockIdx.x & 511) << 8) | (int)threadIdx.x;
    const int bv = bv_base + ((int)blockIdx.x >> 9);
    const int b  = bv / Vc;

    const float px = pts[(b * 3 + 0) * Nc + n];
    const float py = pts[(b * 3 + 1) * Nc + n];
    const float pz = pts[(b * 3 + 2) * Nc + n];

    const float* E = Emat + bv * 12;
    const float xx = E[0] * px + E[1] * py + E[2]  * pz + E[3];
    const float yy = E[4] * px + E[5] * py + E[6]  * pz + E[7];
    const float zz = E[8] * px + E[9] * py + E[10] * pz + E[11];

    const float* K = Kmat + bv * 9;
    const float inv_z = 1.0f / zz;
    const float nx = xx * inv_z;
    const float ny = yy * inv_z;
    const float u = K[0] * nx + K[1] * ny + K[2];
    const float v = K[3] * nx + K[4] * ny + K[5];

    const float gx = (u - 0.5f) * (2.0f / (float)(Wc - 1)) - 1.0f;
    const float gy = (v - 0.5f) * (2.0f / (float)(Hc - 1)) - 1.0f;
    const float ix = ((gx + 1.0f) * (float)Wc - 1.0f) * 0.5f;
    const float iy = ((gy + 1.0f) * (float)Hc - 1.0f) * 0.5f;
    const float sx = (float)Wc / (float)(Wc - 1);  // grid dx in pixel space
    const float sy = (float)Hc / (float)(Hc - 1);

    int xc0, xc1, xl0, xl1, xr0, xr1;
    int yc0, yc1, yt0, yt1, yb0, yb1;
    float wxc0, wxc1, wxl0, wxl1, wxr0, wxr1;
    float wyc0, wyc1, wyt0, wyt1, wyb0, wyb1;
    axis_decomp(ix,      Wc, xc0, xc1, wxc0, wxc1);
    axis_decomp(ix - sx, Wc, xl0, xl1, wxl0, wxl1);
    axis_decomp(ix + sx, Wc, xr0, xr1, wxr0, wxr1);
    axis_decomp(iy,      Hc, yc0, yc1, wyc0, wyc1);
    axis_decomp(iy - sy, Hc, yt0, yt1, wyt0, wyt1);
    axis_decomp(iy + sy, Hc, yb0, yb1, wyb0, wyb1);

    float4 accF[4], accGx[4], accGy[4];
#pragma unroll
    for (int j = 0; j < 4; ++j) {
        accF[j]  = make_float4(0.f, 0.f, 0.f, 0.f);
        accGx[j] = make_float4(0.f, 0.f, 0.f, 0.f);
        accGy[j] = make_float4(0.f, 0.f, 0.f, 0.f);
    }

    const float* plane = fmt + (size_t)bv * HWc * 16;

    auto tap = [&](int x, int y, float w, float4* acc) {
        const float4* p = reinterpret_cast<const float4*>(plane + (size_t)(y * Wc + x) * 16);
#pragma unroll
        for (int j = 0; j < 4; ++j) {
            float4 vv = p[j];
            acc[j].x += w * vv.x;
            acc[j].y += w * vv.y;
            acc[j].z += w * vv.z;
            acc[j].w += w * vv.w;
        }
    };
    auto sample = [&](int x0, int x1, float wx0, float wx1,
                      int y0, int y1, float wy0, float wy1,
                      float4* acc, float s) {
        tap(x0, y0, s * wx0 * wy0, acc);
        tap(x1, y0, s * wx1 * wy0, acc);
        tap(x0, y1, s * wx0 * wy1, acc);
        tap(x1, y1, s * wx1 * wy1, acc);
    };

    sample(xc0, xc1, wxc0, wxc1, yc0, yc1, wyc0, wyc1, accF,  1.0f);
    sample(xl0, xl1, wxl0, wxl1, yc0, yc1, wyc0, wyc1, accGx, -0.5f);
    sample(xr0, xr1, wxr0, wxr1, yc0, yc1, wyc0, wyc1, accGx,  0.5f);
    sample(xc0, xc1, wxc0, wxc1, yt0, yt1, wyt0, wyt1, accGy, -0.5f);
    sample(xc0, xc1, wxc0, wxc1, yb0, yb1, wyb0, wyb1, accGy,  0.5f);

#pragma unroll
    for (int j = 0; j < 4; ++j) {
        float fs[4]  = {accF[j].x,  accF[j].y,  accF[j].z,  accF[j].w};
        float gxs[4] = {accGx[j].x, accGx[j].y, accGx[j].z, accGx[j].w};
        float gys[4] = {accGy[j].x, accGy[j].y, accGy[j].z, accGy[j].w};
#pragma unroll
        for (int k = 0; k < 4; ++k) {
            const int c = 4 * j + k;
            const size_t o = (size_t)(bv * 16 + c) * Nc + n;
            // nontemporal: pure streaming output, keep it out of L2/L3 so
            // fmt tap lines stay resident.
            __builtin_nontemporal_store(fs[k], out_f + o);
            f32x2 g2 = {gxs[k], gys[k]};
            __builtin_nontemporal_store(g2, reinterpret_cast<f32x2*>(out_g) + o);
        }
    }
}

// ---- R1 fallback (thread per (bv,c,n), direct from (BV,C,H,W)) ----
__device__ __forceinline__ float bilin(const float* __restrict__ base,
                                       int x0, int x1, float wx0, float wx1,
                                       int y0, int y1, float wy0, float wy1) {
    const float* r0 = base + y0 * Wc;
    const float* r1 = base + y1 * Wc;
    return wy0 * (wx0 * r0[x0] + wx1 * r0[x1]) +
           wy1 * (wx0 * r1[x0] + wx1 * r1[x1]);
}

__global__ __launch_bounds__(256) void fgf_fallback_kernel(
    const float* __restrict__ fm, const float* __restrict__ pts,
    const float* __restrict__ Kmat, const float* __restrict__ Emat,
    float* __restrict__ out_f, float* __restrict__ out_g) {
    const int n   = (((int)blockIdx.x & 511) << 8) | (int)threadIdx.x;
    const int bvc = (int)blockIdx.x >> 9;
    const int bv  = bvc >> 4;
    const int b   = bv / Vc;

    const float px = pts[(b * 3 + 0) * Nc + n];
    const float py = pts[(b * 3 + 1) * Nc + n];
    const float pz = pts[(b * 3 + 2) * Nc + n];
    const float* E = Emat + bv * 12;
    const float xx = E[0] * px + E[1] * py + E[2]  * pz + E[3];
    const float yy = E[4] * px + E[5] * py + E[6]  * pz + E[7];
    const float zz = E[8] * px + E[9] * py + E[10] * pz + E[11];
    const float* K = Kmat + bv * 9;
    const float inv_z = 1.0f / zz;
    const float u = K[0] * (xx * inv_z) + K[1] * (yy * inv_z) + K[2];
    const float v = K[3] * (xx * inv_z) + K[4] * (yy * inv_z) + K[5];
    const float gx = (u - 0.5f) * (2.0f / (float)(Wc - 1)) - 1.0f;
    const float gy = (v - 0.5f) * (2.0f / (float)(Hc - 1)) - 1.0f;
    const float ix = ((gx + 1.0f) * (float)Wc - 1.0f) * 0.5f;
    const float iy = ((gy + 1.0f) * (float)Hc - 1.0f) * 0.5f;
    const float sx = (float)Wc / (float)(Wc - 1);
    const float sy = (float)Hc / (float)(Hc - 1);

    int xc0, xc1, xl0, xl1, xr0, xr1, yc0, yc1, yt0, yt1, yb0, yb1;
    float wxc0, wxc1, wxl0, wxl1, wxr0, wxr1, wyc0, wyc1, wyt0, wyt1, wyb0, wyb1;
    axis_decomp(ix,      Wc, xc0, xc1, wxc0, wxc1);
    axis_decomp(ix - sx, Wc, xl0, xl1, wxl0, wxl1);
    axis_decomp(ix + sx, Wc, xr0, xr1, wxr0, wxr1);
    axis_decomp(iy,      Hc, yc0, yc1, wyc0, wyc1);
    axis_decomp(iy - sy, Hc, yt0, yt1, wyt0, wyt1);
    axis_decomp(iy + sy, Hc, yb0, yb1, wyb0, wyb1);

    const float* base = fm + (size_t)bvc * HWc;
    const float fc = bilin(base, xc0, xc1, wxc0, wxc1, yc0, yc1, wyc0, wyc1);
    const float fl = bilin(base, xl0, xl1, wxl0, wxl1, yc0, yc1, wyc0, wyc1);
    const float fr = bilin(base, xr0, xr1, wxr0, wxr1, yc0, yc1, wyc0, wyc1);
    const float ft = bilin(base, xc0, xc1, wxc0, wxc1, yt0, yt1, wyt0, wyt1);
    const float fb = bilin(base, xc0, xc1, wxc0, wxc1, yb0, yb1, wyb0, wyb1);

    const size_t out_idx = (size_t)blockIdx.x * 256 + threadIdx.x;
    out_f[out_idx] = fc;
    *reinterpret_cast<float2*>(out_g + out_idx * 2) =
        make_float2(0.5f * (fr - fl), 0.5f * (fb - ft));
}

}  // namespace

extern "C" void kernel_launch(void* const* d_in, const int* in_sizes, int n_in,
                              void* d_out, int out_size, void* d_ws, size_t ws_size,
                              hipStream_t stream) {
    const float* fm  = (const float*)d_in[0];
    const float* pts = (const float*)d_in[1];
    const float* K   = (const float*)d_in[2];
    const float* E   = (const float*)d_in[3];
    float* out_f = (float*)d_out;
    float* out_g = out_f + (size_t)BVc * Cc * Nc;

    if (ws_size >= FMT_BYTES) {
        float* fmt = (float*)d_ws;
        for (int g = 0; g < BVc; g += BV_CHUNK) {
            transpose_kernel<<<BV_CHUNK * (HWc / 256), 256, 0, stream>>>(fm, fmt, g);
            gather_kernel<<<BV_CHUNK * (Nc / 256), 256, 0, stream>>>(
                fmt, pts, K, E, out_f, out_g, g);
        }
    } else {
        fgf_fallback_kernel<<<BVc * Cc * (Nc / 256), 256, 0, stream>>>(
            fm, pts, K, E, out_f, out_g);
    }
}

// Round 4
// 1017.378 us; speedup vs baseline: 1.0505x; 1.0505x over previous
//
#include <hip/hip_runtime.h>

// FeatureGradFetcher: B=2 V=5 C=16 H=512 W=640 N=131072
// out = concat(f (B,V,C,N), f_grad (B,V,C,N,2)) flat, float32.
//
// R5: counting-sort points by image row + XCD-affine sorted gather.
//  - R3/R4 evidence: gather fetches 2.19GB (10x compulsory) because random
//    points spread each plane's lines across all 8 XCD L2s (4MB each vs
//    21MB plane): ~zero reuse, multi-XCD duplication. L3 residency (R4)
//    didn't help -> the L2-miss path itself is the limiter.
//  - Fix: sort (bv,n) by y0 (512-bin counting sort). Gather block B takes
//    sorted chunk j=(B&7)*64+(B>>3): XCD k=B%8 (hw round-robin) owns a
//    contiguous ~64-row slice (~2.6MB <= 4MB L2). Lines fetched ~once.
//  - Gather writes compact temp[pos][48] via LDS (coalesced); unpermute
//    kernel reads temp[rank[n]] (192B aligned granules), LDS-transposes,
//    writes c-major output coalesced+nontemporal. (Direct scattered writes
//    to out[n] would RMW-amplify 252MB -> ~4GB; hence the temp+unpermute.)
//  - 4-bv chunks: fmt 84MB + temp 101MB + idx/rank 10.5MB = 186MB <= ws
//    (prior rounds proved ws >= 210MB).
// Math per (bv,n) is op-identical to R3 -> bitwise-same outputs.

namespace {
constexpr int Bc = 2, Vc = 5, Cc = 16, Hc = 512, Wc = 640;
constexpr int Nc = 131072;
constexpr int BVc = Bc * Vc;
constexpr int HWc = Hc * Wc;
constexpr int CHUNK = 4;  // bv planes per pipeline stage

constexpr size_t FMT_CH  = (size_t)CHUNK * HWc * Cc * sizeof(float);   //  83,886,080
constexpr size_t TEMP_CH = (size_t)CHUNK * Nc * 48 * sizeof(float);    // 100,663,296
constexpr size_t IDX_B   = (size_t)BVc * Nc * sizeof(int);             //   5,242,880
constexpr size_t CNT_B   = (size_t)BVc * 512 * sizeof(unsigned);       //      20,480
constexpr size_t OFF_FMT  = 0;
constexpr size_t OFF_TEMP = OFF_FMT + FMT_CH;
constexpr size_t OFF_IDX  = OFF_TEMP + TEMP_CH;
constexpr size_t OFF_RANK = OFF_IDX + IDX_B;
constexpr size_t OFF_CNT  = OFF_RANK + IDX_B;
constexpr size_t OFF_CUR  = OFF_CNT + CNT_B;
constexpr size_t WS_NEED  = OFF_CUR + CNT_B;                           // ~195 MB

typedef float f32x2 __attribute__((ext_vector_type(2)));
typedef float f32x4 __attribute__((ext_vector_type(4)));

__device__ __forceinline__ void axis_decomp(float t, int limit,
                                            int& i0, int& i1,
                                            float& w0, float& w1) {
    float f0 = floorf(t);
    float fr = t - f0;
    float f1 = f0 + 1.0f;
    float lim = (float)(limit - 1);
    w0 = (1.0f - fr) * ((f0 >= 0.0f && f0 <= lim) ? 1.0f : 0.0f);
    w1 = fr * ((f1 >= 0.0f && f1 <= lim) ? 1.0f : 0.0f);
    int i = (int)f0;
    i0 = min(max(i, 0), limit - 1);
    i1 = min(max(i + 1, 0), limit - 1);
}

// Projection (bit-identical op order to the gather's prologue).
__device__ __forceinline__ void project(const float* __restrict__ pts,
                                        const float* __restrict__ Kmat,
                                        const float* __restrict__ Emat,
                                        int bv, int n, float& ix, float& iy) {
    const int b = bv / Vc;
    const float px = pts[(b * 3 + 0) * Nc + n];
    const float py = pts[(b * 3 + 1) * Nc + n];
    const float pz = pts[(b * 3 + 2) * Nc + n];
    const float* E = Emat + bv * 12;
    const float xx = E[0] * px + E[1] * py + E[2]  * pz + E[3];
    const float yy = E[4] * px + E[5] * py + E[6]  * pz + E[7];
    const float zz = E[8] * px + E[9] * py + E[10] * pz + E[11];
    const float* K = Kmat + bv * 9;
    const float inv_z = 1.0f / zz;
    const float nx = xx * inv_z;
    const float ny = yy * inv_z;
    const float u = K[0] * nx + K[1] * ny + K[2];
    const float v = K[3] * nx + K[4] * ny + K[5];
    const float gx = (u - 0.5f) * (2.0f / (float)(Wc - 1)) - 1.0f;
    const float gy = (v - 0.5f) * (2.0f / (float)(Hc - 1)) - 1.0f;
    ix = ((gx + 1.0f) * (float)Wc - 1.0f) * 0.5f;
    iy = ((gy + 1.0f) * (float)Hc - 1.0f) * 0.5f;
}

// ---- binning: counting sort by y0 ----
__global__ void zero_kernel(unsigned* __restrict__ counts) {
    const int i = (int)blockIdx.x * 256 + (int)threadIdx.x;
    if (i < BVc * 512) counts[i] = 0u;
}

__global__ __launch_bounds__(256) void count_kernel(
    const float* __restrict__ pts, const float* __restrict__ Kmat,
    const float* __restrict__ Emat, unsigned* __restrict__ counts) {
    const int n  = (((int)blockIdx.x & 511) << 8) | (int)threadIdx.x;
    const int bv = (int)blockIdx.x >> 9;
    float ix, iy;
    project(pts, Kmat, Emat, bv, n, ix, iy);
    const int y0 = min(max((int)floorf(iy), 0), Hc - 1);
    atomicAdd(&counts[bv * 512 + y0], 1u);
}

__global__ void prefix_kernel(const unsigned* __restrict__ counts,
                              unsigned* __restrict__ cursors) {
    const int t = (int)threadIdx.x;
    if (t < BVc) {
        unsigned s = 0;
        for (int y = 0; y < 512; ++y) {
            const unsigned c = counts[t * 512 + y];
            cursors[t * 512 + y] = s;
            s += c;
        }
    }
}

__global__ __launch_bounds__(256) void scatter_kernel(
    const float* __restrict__ pts, const float* __restrict__ Kmat,
    const float* __restrict__ Emat, unsigned* __restrict__ cursors,
    int* __restrict__ idx, int* __restrict__ rank) {
    const int n  = (((int)blockIdx.x & 511) << 8) | (int)threadIdx.x;
    const int bv = (int)blockIdx.x >> 9;
    float ix, iy;
    project(pts, Kmat, Emat, bv, n, ix, iy);
    const int y0 = min(max((int)floorf(iy), 0), Hc - 1);
    const unsigned pos = atomicAdd(&cursors[bv * 512 + y0], 1u);
    idx[bv * Nc + (int)pos] = n;
    rank[bv * Nc + n] = (int)pos;
}

// ---- fm (BV,C,H,W) -> fmt chunk (bvl,H,W,C) ----
__global__ __launch_bounds__(256) void transpose_kernel(
    const float* __restrict__ fm, float* __restrict__ fmt, int bv_base) {
    __shared__ float lds[16 * 256];
    const int blocks_per_bv = HWc / 256;  // 1280
    const int bvl = (int)blockIdx.x / blocks_per_bv;
    const int bv = bv_base + bvl;
    const int pix0 = ((int)blockIdx.x % blocks_per_bv) * 256;
    const int t = (int)threadIdx.x;
#pragma unroll
    for (int i = 0; i < 4; ++i) {
        const int l = i * 256 + t;   // float4 slot 0..1023
        const int c = l >> 6;        // channel 0..15
        const int m = l & 63;        // float4 within the 256-px channel row
        const float4 v = *reinterpret_cast<const float4*>(
            fm + (size_t)(bv * 16 + c) * HWc + pix0 + 4 * m);
        *reinterpret_cast<float4*>(&lds[c * 256 + 4 * m]) = v;
    }
    __syncthreads();
    float4* dst = reinterpret_cast<float4*>(fmt + (size_t)(bvl * HWc + pix0) * 16);
#pragma unroll
    for (int j = 0; j < 4; ++j) {
        const int q = j * 256 + t;
        const int p = q >> 2;
        const int k = q & 3;
        float4 v;
        v.x = lds[(4 * k + 0) * 256 + p];
        v.y = lds[(4 * k + 1) * 256 + p];
        v.z = lds[(4 * k + 2) * 256 + p];
        v.w = lds[(4 * k + 3) * 256 + p];
        dst[q] = v;
    }
}

// ---- sorted gather: block B -> sorted chunk j=(B&7)*64+(B>>3) ----
// XCD = B%8 (hw round-robin) gets a contiguous y-slice of the sorted array.
__global__ __launch_bounds__(256) void gather_sorted_kernel(
    const float* __restrict__ fmt,   // chunk (bvl, H, W, C)
    const float* __restrict__ pts,
    const float* __restrict__ Kmat,
    const float* __restrict__ Emat,
    const int* __restrict__ idx,     // (BV, N) pos -> n
    float* __restrict__ temp,        // chunk (bvl, N, 48)
    int bv_base) {
    __shared__ float lds[256 * 48];  // 48KB: [point][48] results
    const int t = (int)threadIdx.x;
    const int bvl = (int)blockIdx.x >> 9;
    const int B = (int)blockIdx.x & 511;
    const int j = ((B & 7) << 6) | (B >> 3);  // bijective chunk remap
    const int pos = (j << 8) | t;
    const int bv = bv_base + bvl;
    const int n = idx[bv * Nc + pos];
    const int b = bv / Vc;

    const float px = pts[(b * 3 + 0) * Nc + n];
    const float py = pts[(b * 3 + 1) * Nc + n];
    const float pz = pts[(b * 3 + 2) * Nc + n];
    const float* E = Emat + bv * 12;
    const float xx = E[0] * px + E[1] * py + E[2]  * pz + E[3];
    const float yy = E[4] * px + E[5] * py + E[6]  * pz + E[7];
    const float zz = E[8] * px + E[9] * py + E[10] * pz + E[11];
    const float* K = Kmat + bv * 9;
    const float inv_z = 1.0f / zz;
    const float nx = xx * inv_z;
    const float ny = yy * inv_z;
    const float u = K[0] * nx + K[1] * ny + K[2];
    const float v = K[3] * nx + K[4] * ny + K[5];
    const float gx = (u - 0.5f) * (2.0f / (float)(Wc - 1)) - 1.0f;
    const float gy = (v - 0.5f) * (2.0f / (float)(Hc - 1)) - 1.0f;
    const float ix = ((gx + 1.0f) * (float)Wc - 1.0f) * 0.5f;
    const float iy = ((gy + 1.0f) * (float)Hc - 1.0f) * 0.5f;
    const float sx = (float)Wc / (float)(Wc - 1);
    const float sy = (float)Hc / (float)(Hc - 1);

    int xc0, xc1, xl0, xl1, xr0, xr1;
    int yc0, yc1, yt0, yt1, yb0, yb1;
    float wxc0, wxc1, wxl0, wxl1, wxr0, wxr1;
    float wyc0, wyc1, wyt0, wyt1, wyb0, wyb1;
    axis_decomp(ix,      Wc, xc0, xc1, wxc0, wxc1);
    axis_decomp(ix - sx, Wc, xl0, xl1, wxl0, wxl1);
    axis_decomp(ix + sx, Wc, xr0, xr1, wxr0, wxr1);
    axis_decomp(iy,      Hc, yc0, yc1, wyc0, wyc1);
    axis_decomp(iy - sy, Hc, yt0, yt1, wyt0, wyt1);
    axis_decomp(iy + sy, Hc, yb0, yb1, wyb0, wyb1);

    float4 accF[4], accGx[4], accGy[4];
#pragma unroll
    for (int q = 0; q < 4; ++q) {
        accF[q]  = make_float4(0.f, 0.f, 0.f, 0.f);
        accGx[q] = make_float4(0.f, 0.f, 0.f, 0.f);
        accGy[q] = make_float4(0.f, 0.f, 0.f, 0.f);
    }

    const float* plane = fmt + (size_t)bvl * HWc * 16;

    auto tap = [&](int x, int y, float w, float4* acc) {
        const float4* p = reinterpret_cast<const float4*>(plane + (size_t)(y * Wc + x) * 16);
#pragma unroll
        for (int q = 0; q < 4; ++q) {
            float4 vv = p[q];
            acc[q].x += w * vv.x;
            acc[q].y += w * vv.y;
            acc[q].z += w * vv.z;
            acc[q].w += w * vv.w;
        }
    };
    auto sample = [&](int x0, int x1, float wx0, float wx1,
                      int y0, int y1, float wy0, float wy1,
                      float4* acc, float s) {
        tap(x0, y0, s * wx0 * wy0, acc);
        tap(x1, y0, s * wx1 * wy0, acc);
        tap(x0, y1, s * wx0 * wy1, acc);
        tap(x1, y1, s * wx1 * wy1, acc);
    };

    sample(xc0, xc1, wxc0, wxc1, yc0, yc1, wyc0, wyc1, accF,  1.0f);
    sample(xl0, xl1, wxl0, wxl1, yc0, yc1, wyc0, wyc1, accGx, -0.5f);
    sample(xr0, xr1, wxr0, wxr1, yc0, yc1, wyc0, wyc1, accGx,  0.5f);
    sample(xc0, xc1, wxc0, wxc1, yt0, yt1, wyt0, wyt1, accGy, -0.5f);
    sample(xc0, xc1, wxc0, wxc1, yb0, yb1, wyb0, wyb1, accGy,  0.5f);

    // stage results: lds[point t][48]; comps 0..15 = f, 16+2c = gx, 17+2c = gy
    float* lb = lds + t * 48;
#pragma unroll
    for (int q = 0; q < 4; ++q) {
        const float fs[4]  = {accF[q].x,  accF[q].y,  accF[q].z,  accF[q].w};
        const float gxs[4] = {accGx[q].x, accGx[q].y, accGx[q].z, accGx[q].w};
        const float gys[4] = {accGy[q].x, accGy[q].y, accGy[q].z, accGy[q].w};
#pragma unroll
        for (int k = 0; k < 4; ++k) {
            const int c = 4 * q + k;
            lb[c]           = fs[k];
            lb[16 + 2 * c]  = gxs[k];
            lb[17 + 2 * c]  = gys[k];
        }
    }
    __syncthreads();
    // coalesced 48KB contiguous store of this chunk's [256][48] block
    const f32x4* l4 = reinterpret_cast<const f32x4*>(lds);
    f32x4* t4 = reinterpret_cast<f32x4*>(temp) + (size_t)(bvl * Nc + (j << 8)) * 12;
#pragma unroll
    for (int i = 0; i < 12; ++i) {
        __builtin_nontemporal_store(l4[i * 256 + t], t4 + i * 256 + t);
    }
}

// ---- unpermute: out[n] <- temp[rank[n]], LDS transpose to c-major ----
__global__ __launch_bounds__(256) void unpermute_kernel(
    const float* __restrict__ temp, const int* __restrict__ rank,
    float* __restrict__ out_f, float* __restrict__ out_g, int bv_base) {
    __shared__ float lds[48 * 260];  // [comp][point], padded rows
    const int t = (int)threadIdx.x;
    const int bvl = (int)blockIdx.x >> 9;
    const int n0 = ((int)blockIdx.x & 511) << 8;
    const int bv = bv_base + bvl;
    const int n = n0 + t;
    const int pos = rank[bv * Nc + n];
    const f32x4* t4 = reinterpret_cast<const f32x4*>(temp) + (size_t)(bvl * Nc + pos) * 12;
#pragma unroll
    for (int q = 0; q < 12; ++q) {
        f32x4 v = __builtin_nontemporal_load(t4 + q);  // 192B aligned granule
        lds[(4 * q + 0) * 260 + t] = v.x;
        lds[(4 * q + 1) * 260 + t] = v.y;
        lds[(4 * q + 2) * 260 + t] = v.z;
        lds[(4 * q + 3) * 260 + t] = v.w;
    }
    __syncthreads();
#pragma unroll
    for (int c = 0; c < 16; ++c) {
        __builtin_nontemporal_store(lds[c * 260 + t],
                                    out_f + (size_t)(bv * 16 + c) * Nc + n);
        f32x2 g2 = {lds[(16 + 2 * c) * 260 + t], lds[(17 + 2 * c) * 260 + t]};
        __builtin_nontemporal_store(g2, reinterpret_cast<f32x2*>(out_g) +
                                            (size_t)(bv * 16 + c) * Nc + n);
    }
}

// ---- fallback (thread per (bv,c,n), direct from (BV,C,H,W)) ----
__device__ __forceinline__ float bilin(const float* __restrict__ base,
                                       int x0, int x1, float wx0, float wx1,
                                       int y0, int y1, float wy0, float wy1) {
    const float* r0 = base + y0 * Wc;
    const float* r1 = base + y1 * Wc;
    return wy0 * (wx0 * r0[x0] + wx1 * r0[x1]) +
           wy1 * (wx0 * r1[x0] + wx1 * r1[x1]);
}

__global__ __launch_bounds__(256) void fgf_fallback_kernel(
    const float* __restrict__ fm, const float* __restrict__ pts,
    const float* __restrict__ Kmat, const float* __restrict__ Emat,
    float* __restrict__ out_f, float* __restrict__ out_g) {
    const int n   = (((int)blockIdx.x & 511) << 8) | (int)threadIdx.x;
    const int bvc = (int)blockIdx.x >> 9;
    const int bv  = bvc >> 4;
    float ix, iy;
    project(pts, Kmat, Emat, bv, n, ix, iy);
    const float sx = (float)Wc / (float)(Wc - 1);
    const float sy = (float)Hc / (float)(Hc - 1);

    int xc0, xc1, xl0, xl1, xr0, xr1, yc0, yc1, yt0, yt1, yb0, yb1;
    float wxc0, wxc1, wxl0, wxl1, wxr0, wxr1, wyc0, wyc1, wyt0, wyt1, wyb0, wyb1;
    axis_decomp(ix,      Wc, xc0, xc1, wxc0, wxc1);
    axis_decomp(ix - sx, Wc, xl0, xl1, wxl0, wxl1);
    axis_decomp(ix + sx, Wc, xr0, xr1, wxr0, wxr1);
    axis_decomp(iy,      Hc, yc0, yc1, wyc0, wyc1);
    axis_decomp(iy - sy, Hc, yt0, yt1, wyt0, wyt1);
    axis_decomp(iy + sy, Hc, yb0, yb1, wyb0, wyb1);

    const float* base = fm + (size_t)bvc * HWc;
    const float fc = bilin(base, xc0, xc1, wxc0, wxc1, yc0, yc1, wyc0, wyc1);
    const float fl = bilin(base, xl0, xl1, wxl0, wxl1, yc0, yc1, wyc0, wyc1);
    const float fr = bilin(base, xr0, xr1, wxr0, wxr1, yc0, yc1, wyc0, wyc1);
    const float ft = bilin(base, xc0, xc1, wxc0, wxc1, yt0, yt1, wyt0, wyt1);
    const float fb = bilin(base, xc0, xc1, wxc0, wxc1, yb0, yb1, wyb0, wyb1);

    const size_t out_idx = (size_t)blockIdx.x * 256 + threadIdx.x;
    out_f[out_idx] = fc;
    *reinterpret_cast<float2*>(out_g + out_idx * 2) =
        make_float2(0.5f * (fr - fl), 0.5f * (fb - ft));
}

}  // namespace

extern "C" void kernel_launch(void* const* d_in, const int* in_sizes, int n_in,
                              void* d_out, int out_size, void* d_ws, size_t ws_size,
                              hipStream_t stream) {
    const float* fm  = (const float*)d_in[0];
    const float* pts = (const float*)d_in[1];
    const float* K   = (const float*)d_in[2];
    const float* E   = (const float*)d_in[3];
    float* out_f = (float*)d_out;
    float* out_g = out_f + (size_t)BVc * Cc * Nc;

    if (ws_size >= WS_NEED) {
        char* ws = (char*)d_ws;
        float*    fmt     = (float*)(ws + OFF_FMT);
        float*    temp    = (float*)(ws + OFF_TEMP);
        int*      idx     = (int*)(ws + OFF_IDX);
        int*      rank    = (int*)(ws + OFF_RANK);
        unsigned* counts  = (unsigned*)(ws + OFF_CNT);
        unsigned* cursors = (unsigned*)(ws + OFF_CUR);

        zero_kernel<<<(BVc * 512 + 255) / 256, 256, 0, stream>>>(counts);
        count_kernel<<<BVc * (Nc / 256), 256, 0, stream>>>(pts, K, E, counts);
        prefix_kernel<<<1, 256, 0, stream>>>(counts, cursors);
        scatter_kernel<<<BVc * (Nc / 256), 256, 0, stream>>>(pts, K, E, cursors, idx, rank);

        for (int g = 0; g < BVc; g += CHUNK) {
            const int cs = min(CHUNK, BVc - g);
            transpose_kernel<<<cs * (HWc / 256), 256, 0, stream>>>(fm, fmt, g);
            gather_sorted_kernel<<<cs * (Nc / 256), 256, 0, stream>>>(
                fmt, pts, K, E, idx, temp, g);
            unpermute_kernel<<<cs * (Nc / 256), 256, 0, stream>>>(
                temp, rank, out_f, out_g, g);
        }
    } else {
        fgf_fallback_kernel<<<BVc * Cc * (Nc / 256), 256, 0, stream>>>(
            fm, pts, K, E, out_f, out_g);
    }
}

// Round 5
// 818.756 us; speedup vs baseline: 1.3054x; 1.2426x over previous
//
#include <hip/hip_runtime.h>

// FeatureGradFetcher: B=2 V=5 C=16 H=512 W=640 N=131072
// out = concat(f (B,V,C,N), f_grad (B,V,C,N,2)) flat, float32.
//
// R6: deterministic counting sort (no global atomics).
//  - R5 evidence: scatter_kernel = 151.8us, HBM 4.5%, VALU 1.2% -> bound by
//    1.31M atomicAdd-with-return chains (~256-deep per bin cursor). count_kernel
//    paid a similar tax. Sort overhead ~ cancelled the sorted-gather win
//    (gather dispatches all dropped below 152us vs 697us monolithic).
//  - Fix: hist (LDS atomics only) -> block-level exclusive scan -> bin-base
//    prefix -> scatter by computed position. Zero global atomics, all
//    coalesced or L2-hot accesses. Bijective by construction; sort order only
//    affects locality, not correctness.
//  - Gather/unpermute/transpose unchanged from R5.

namespace {
constexpr int Bc = 2, Vc = 5, Cc = 16, Hc = 512, Wc = 640;
constexpr int Nc = 131072;
constexpr int BVc = Bc * Vc;
constexpr int HWc = Hc * Wc;
constexpr int CHUNK = 4;           // bv planes per pipeline stage
constexpr int NBIN = 128;          // y-bins (4 rows each)
constexpr int NBLK = Nc / 256;     // 512 point-blocks per bv

constexpr size_t FMT_CH   = (size_t)CHUNK * HWc * Cc * sizeof(float);   //  83,886,080
constexpr size_t TEMP_CH  = (size_t)CHUNK * Nc * 48 * sizeof(float);    // 100,663,296
constexpr size_t IDX_B    = (size_t)BVc * Nc * sizeof(int);             //   5,242,880
constexpr size_t HIST_B   = (size_t)BVc * NBIN * NBLK * sizeof(unsigned); // 2,621,440
constexpr size_t TOT_B    = (size_t)BVc * NBIN * sizeof(unsigned);      //       5,120
constexpr size_t OFF_FMT   = 0;
constexpr size_t OFF_TEMP  = OFF_FMT + FMT_CH;
constexpr size_t OFF_IDX   = OFF_TEMP + TEMP_CH;
constexpr size_t OFF_RANK  = OFF_IDX + IDX_B;
constexpr size_t OFF_PACK  = OFF_RANK + IDX_B;
constexpr size_t OFF_HIST  = OFF_PACK + IDX_B;
constexpr size_t OFF_OFFT  = OFF_HIST + HIST_B;
constexpr size_t OFF_TOT   = OFF_OFFT + HIST_B;
constexpr size_t OFF_BASE  = OFF_TOT + TOT_B;
constexpr size_t WS_NEED   = OFF_BASE + TOT_B;   // ~205.5 MB (ws proven >= 209.7 MB)

typedef float f32x2 __attribute__((ext_vector_type(2)));
typedef float f32x4 __attribute__((ext_vector_type(4)));

__device__ __forceinline__ void axis_decomp(float t, int limit,
                                            int& i0, int& i1,
                                            float& w0, float& w1) {
    float f0 = floorf(t);
    float fr = t - f0;
    float f1 = f0 + 1.0f;
    float lim = (float)(limit - 1);
    w0 = (1.0f - fr) * ((f0 >= 0.0f && f0 <= lim) ? 1.0f : 0.0f);
    w1 = fr * ((f1 >= 0.0f && f1 <= lim) ? 1.0f : 0.0f);
    int i = (int)f0;
    i0 = min(max(i, 0), limit - 1);
    i1 = min(max(i + 1, 0), limit - 1);
}

__device__ __forceinline__ void project(const float* __restrict__ pts,
                                        const float* __restrict__ Kmat,
                                        const float* __restrict__ Emat,
                                        int bv, int n, float& ix, float& iy) {
    const int b = bv / Vc;
    const float px = pts[(b * 3 + 0) * Nc + n];
    const float py = pts[(b * 3 + 1) * Nc + n];
    const float pz = pts[(b * 3 + 2) * Nc + n];
    const float* E = Emat + bv * 12;
    const float xx = E[0] * px + E[1] * py + E[2]  * pz + E[3];
    const float yy = E[4] * px + E[5] * py + E[6]  * pz + E[7];
    const float zz = E[8] * px + E[9] * py + E[10] * pz + E[11];
    const float* K = Kmat + bv * 9;
    const float inv_z = 1.0f / zz;
    const float nx = xx * inv_z;
    const float ny = yy * inv_z;
    const float u = K[0] * nx + K[1] * ny + K[2];
    const float v = K[3] * nx + K[4] * ny + K[5];
    const float gx = (u - 0.5f) * (2.0f / (float)(Wc - 1)) - 1.0f;
    const float gy = (v - 0.5f) * (2.0f / (float)(Hc - 1)) - 1.0f;
    ix = ((gx + 1.0f) * (float)Wc - 1.0f) * 0.5f;
    iy = ((gy + 1.0f) * (float)Hc - 1.0f) * 0.5f;
}

// ---- sort step 1: per-block LDS histogram + packed (bin,lrank) ----
__global__ __launch_bounds__(256) void hist_kernel(
    const float* __restrict__ pts, const float* __restrict__ Kmat,
    const float* __restrict__ Emat,
    unsigned* __restrict__ histT,    // (BVc*NBIN) rows x NBLK cols
    unsigned* __restrict__ packed) { // (BVc, Nc): bin<<16 | lrank
    __shared__ unsigned lh[NBIN];
    const int t = (int)threadIdx.x;
    const int blk = (int)blockIdx.x & (NBLK - 1);
    const int bv = (int)blockIdx.x >> 9;
    const int n = (blk << 8) | t;
    if (t < NBIN) lh[t] = 0u;
    __syncthreads();
    float ix, iy;
    project(pts, Kmat, Emat, bv, n, ix, iy);
    const int y0 = min(max((int)floorf(iy), 0), Hc - 1);
    const unsigned bin = (unsigned)(y0 >> 2);  // 4 rows per bin
    const unsigned lrank = atomicAdd(&lh[bin], 1u);  // LDS atomic: no chains
    packed[bv * Nc + n] = (bin << 16) | lrank;
    __syncthreads();
    if (t < NBIN) histT[(size_t)((bv * NBIN) + t) * NBLK + blk] = lh[t];
}

// ---- sort step 2: exclusive scan over blocks, per (bv,bin) row ----
__global__ __launch_bounds__(512) void scan_kernel(
    const unsigned* __restrict__ histT, unsigned* __restrict__ offT,
    unsigned* __restrict__ totals) {
    __shared__ unsigned s[NBLK];
    const int row = (int)blockIdx.x;   // bv*NBIN + bin
    const int t = (int)threadIdx.x;    // blk
    const unsigned own = histT[(size_t)row * NBLK + t];
    s[t] = own;
    __syncthreads();
#pragma unroll
    for (int off = 1; off < NBLK; off <<= 1) {
        const unsigned v = (t >= off) ? s[t - off] : 0u;
        __syncthreads();
        s[t] += v;
        __syncthreads();
    }
    offT[(size_t)row * NBLK + t] = s[t] - own;
    if (t == NBLK - 1) totals[row] = s[t];
}

// ---- sort step 3: per-bv prefix over bins ----
__global__ void base_kernel(const unsigned* __restrict__ totals,
                            unsigned* __restrict__ bin_base) {
    const int bv = (int)threadIdx.x;
    if (bv < BVc) {
        unsigned s = 0;
        for (int b2 = 0; b2 < NBIN; ++b2) {
            bin_base[bv * NBIN + b2] = s;
            s += totals[bv * NBIN + b2];
        }
    }
}

// ---- sort step 4: scatter by computed position (no atomics) ----
__global__ __launch_bounds__(256) void scatter2_kernel(
    const unsigned* __restrict__ packed, const unsigned* __restrict__ offT,
    const unsigned* __restrict__ bin_base,
    int* __restrict__ idx, int* __restrict__ rank) {
    const int t = (int)threadIdx.x;
    const int blk = (int)blockIdx.x & (NBLK - 1);
    const int bv = (int)blockIdx.x >> 9;
    const int n = (blk << 8) | t;
    const unsigned p = packed[bv * Nc + n];
    const unsigned bin = p >> 16;
    const unsigned lrank = p & 0xFFFFu;
    const int row = bv * NBIN + (int)bin;
    const unsigned pos = bin_base[row] + offT[(size_t)row * NBLK + blk] + lrank;
    idx[bv * Nc + (int)pos] = n;
    rank[bv * Nc + n] = (int)pos;
}

// ---- fm (BV,C,H,W) -> fmt chunk (bvl,H,W,C) ----
__global__ __launch_bounds__(256) void transpose_kernel(
    const float* __restrict__ fm, float* __restrict__ fmt, int bv_base) {
    __shared__ float lds[16 * 256];
    const int blocks_per_bv = HWc / 256;  // 1280
    const int bvl = (int)blockIdx.x / blocks_per_bv;
    const int bv = bv_base + bvl;
    const int pix0 = ((int)blockIdx.x % blocks_per_bv) * 256;
    const int t = (int)threadIdx.x;
#pragma unroll
    for (int i = 0; i < 4; ++i) {
        const int l = i * 256 + t;   // float4 slot 0..1023
        const int c = l >> 6;        // channel 0..15
        const int m = l & 63;        // float4 within the 256-px channel row
        const float4 v = *reinterpret_cast<const float4*>(
            fm + (size_t)(bv * 16 + c) * HWc + pix0 + 4 * m);
        *reinterpret_cast<float4*>(&lds[c * 256 + 4 * m]) = v;
    }
    __syncthreads();
    float4* dst = reinterpret_cast<float4*>(fmt + (size_t)(bvl * HWc + pix0) * 16);
#pragma unroll
    for (int j = 0; j < 4; ++j) {
        const int q = j * 256 + t;
        const int p = q >> 2;
        const int k = q & 3;
        float4 v;
        v.x = lds[(4 * k + 0) * 256 + p];
        v.y = lds[(4 * k + 1) * 256 + p];
        v.z = lds[(4 * k + 2) * 256 + p];
        v.w = lds[(4 * k + 3) * 256 + p];
        dst[q] = v;
    }
}

// ---- sorted gather: block B -> sorted chunk j=(B&7)*64+(B>>3) ----
__global__ __launch_bounds__(256) void gather_sorted_kernel(
    const float* __restrict__ fmt,   // chunk (bvl, H, W, C)
    const float* __restrict__ pts,
    const float* __restrict__ Kmat,
    const float* __restrict__ Emat,
    const int* __restrict__ idx,     // (BV, N) pos -> n
    float* __restrict__ temp,        // chunk (bvl, N, 48)
    int bv_base) {
    __shared__ float lds[256 * 48];  // 48KB: [point][48] results
    const int t = (int)threadIdx.x;
    const int bvl = (int)blockIdx.x >> 9;
    const int B = (int)blockIdx.x & 511;
    const int j = ((B & 7) << 6) | (B >> 3);  // XCD-affine bijective remap
    const int pos = (j << 8) | t;
    const int bv = bv_base + bvl;
    const int n = idx[bv * Nc + pos];
    const int b = bv / Vc;

    const float px = pts[(b * 3 + 0) * Nc + n];
    const float py = pts[(b * 3 + 1) * Nc + n];
    const float pz = pts[(b * 3 + 2) * Nc + n];
    const float* E = Emat + bv * 12;
    const float xx = E[0] * px + E[1] * py + E[2]  * pz + E[3];
    const float yy = E[4] * px + E[5] * py + E[6]  * pz + E[7];
    const float zz = E[8] * px + E[9] * py + E[10] * pz + E[11];
    const float* K = Kmat + bv * 9;
    const float inv_z = 1.0f / zz;
    const float nx = xx * inv_z;
    const float ny = yy * inv_z;
    const float u = K[0] * nx + K[1] * ny + K[2];
    const float v = K[3] * nx + K[4] * ny + K[5];
    const float gx = (u - 0.5f) * (2.0f / (float)(Wc - 1)) - 1.0f;
    const float gy = (v - 0.5f) * (2.0f / (float)(Hc - 1)) - 1.0f;
    const float ix = ((gx + 1.0f) * (float)Wc - 1.0f) * 0.5f;
    const float iy = ((gy + 1.0f) * (float)Hc - 1.0f) * 0.5f;
    const float sx = (float)Wc / (float)(Wc - 1);
    const float sy = (float)Hc / (float)(Hc - 1);

    int xc0, xc1, xl0, xl1, xr0, xr1;
    int yc0, yc1, yt0, yt1, yb0, yb1;
    float wxc0, wxc1, wxl0, wxl1, wxr0, wxr1;
    float wyc0, wyc1, wyt0, wyt1, wyb0, wyb1;
    axis_decomp(ix,      Wc, xc0, xc1, wxc0, wxc1);
    axis_decomp(ix - sx, Wc, xl0, xl1, wxl0, wxl1);
    axis_decomp(ix + sx, Wc, xr0, xr1, wxr0, wxr1);
    axis_decomp(iy,      Hc, yc0, yc1, wyc0, wyc1);
    axis_decomp(iy - sy, Hc, yt0, yt1, wyt0, wyt1);
    axis_decomp(iy + sy, Hc, yb0, yb1, wyb0, wyb1);

    float4 accF[4], accGx[4], accGy[4];
#pragma unroll
    for (int q = 0; q < 4; ++q) {
        accF[q]  = make_float4(0.f, 0.f, 0.f, 0.f);
        accGx[q] = make_float4(0.f, 0.f, 0.f, 0.f);
        accGy[q] = make_float4(0.f, 0.f, 0.f, 0.f);
    }

    const float* plane = fmt + (size_t)bvl * HWc * 16;

    auto tap = [&](int x, int y, float w, float4* acc) {
        const float4* p = reinterpret_cast<const float4*>(plane + (size_t)(y * Wc + x) * 16);
#pragma unroll
        for (int q = 0; q < 4; ++q) {
            float4 vv = p[q];
            acc[q].x += w * vv.x;
            acc[q].y += w * vv.y;
            acc[q].z += w * vv.z;
            acc[q].w += w * vv.w;
        }
    };
    auto sample = [&](int x0, int x1, float wx0, float wx1,
                      int y0, int y1, float wy0, float wy1,
                      float4* acc, float s) {
        tap(x0, y0, s * wx0 * wy0, acc);
        tap(x1, y0, s * wx1 * wy0, acc);
        tap(x0, y1, s * wx0 * wy1, acc);
        tap(x1, y1, s * wx1 * wy1, acc);
    };

    sample(xc0, xc1, wxc0, wxc1, yc0, yc1, wyc0, wyc1, accF,  1.0f);
    sample(xl0, xl1, wxl0, wxl1, yc0, yc1, wyc0, wyc1, accGx, -0.5f);
    sample(xr0, xr1, wxr0, wxr1, yc0, yc1, wyc0, wyc1, accGx,  0.5f);
    sample(xc0, xc1, wxc0, wxc1, yt0, yt1, wyt0, wyt1, accGy, -0.5f);
    sample(xc0, xc1, wxc0, wxc1, yb0, yb1, wyb0, wyb1, accGy,  0.5f);

    float* lb = lds + t * 48;
#pragma unroll
    for (int q = 0; q < 4; ++q) {
        const float fs[4]  = {accF[q].x,  accF[q].y,  accF[q].z,  accF[q].w};
        const float gxs[4] = {accGx[q].x, accGx[q].y, accGx[q].z, accGx[q].w};
        const float gys[4] = {accGy[q].x, accGy[q].y, accGy[q].z, accGy[q].w};
#pragma unroll
        for (int k = 0; k < 4; ++k) {
            const int c = 4 * q + k;
            lb[c]           = fs[k];
            lb[16 + 2 * c]  = gxs[k];
            lb[17 + 2 * c]  = gys[k];
        }
    }
    __syncthreads();
    const f32x4* l4 = reinterpret_cast<const f32x4*>(lds);
    f32x4* t4 = reinterpret_cast<f32x4*>(temp) + (size_t)(bvl * Nc + (j << 8)) * 12;
#pragma unroll
    for (int i = 0; i < 12; ++i) {
        __builtin_nontemporal_store(l4[i * 256 + t], t4 + i * 256 + t);
    }
}

// ---- unpermute: out[n] <- temp[rank[n]], LDS transpose to c-major ----
__global__ __launch_bounds__(256) void unpermute_kernel(
    const float* __restrict__ temp, const int* __restrict__ rank,
    float* __restrict__ out_f, float* __restrict__ out_g, int bv_base) {
    __shared__ float lds[48 * 260];
    const int t = (int)threadIdx.x;
    const int bvl = (int)blockIdx.x >> 9;
    const int n0 = ((int)blockIdx.x & 511) << 8;
    const int bv = bv_base + bvl;
    const int n = n0 + t;
    const int pos = rank[bv * Nc + n];
    const f32x4* t4 = reinterpret_cast<const f32x4*>(temp) + (size_t)(bvl * Nc + pos) * 12;
#pragma unroll
    for (int q = 0; q < 12; ++q) {
        f32x4 v = __builtin_nontemporal_load(t4 + q);
        lds[(4 * q + 0) * 260 + t] = v.x;
        lds[(4 * q + 1) * 260 + t] = v.y;
        lds[(4 * q + 2) * 260 + t] = v.z;
        lds[(4 * q + 3) * 260 + t] = v.w;
    }
    __syncthreads();
#pragma unroll
    for (int c = 0; c < 16; ++c) {
        __builtin_nontemporal_store(lds[c * 260 + t],
                                    out_f + (size_t)(bv * 16 + c) * Nc + n);
        f32x2 g2 = {lds[(16 + 2 * c) * 260 + t], lds[(17 + 2 * c) * 260 + t]};
        __builtin_nontemporal_store(g2, reinterpret_cast<f32x2*>(out_g) +
                                            (size_t)(bv * 16 + c) * Nc + n);
    }
}

// ---- fallback (thread per (bv,c,n), direct from (BV,C,H,W)) ----
__device__ __forceinline__ float bilin(const float* __restrict__ base,
                                       int x0, int x1, float wx0, float wx1,
                                       int y0, int y1, float wy0, float wy1) {
    const float* r0 = base + y0 * Wc;
    const float* r1 = base + y1 * Wc;
    return wy0 * (wx0 * r0[x0] + wx1 * r0[x1]) +
           wy1 * (wx0 * r1[x0] + wx1 * r1[x1]);
}

__global__ __launch_bounds__(256) void fgf_fallback_kernel(
    const float* __restrict__ fm, const float* __restrict__ pts,
    const float* __restrict__ Kmat, const float* __restrict__ Emat,
    float* __restrict__ out_f, float* __restrict__ out_g) {
    const int n   = (((int)blockIdx.x & 511) << 8) | (int)threadIdx.x;
    const int bvc = (int)blockIdx.x >> 9;
    const int bv  = bvc >> 4;
    float ix, iy;
    project(pts, Kmat, Emat, bv, n, ix, iy);
    const float sx = (float)Wc / (float)(Wc - 1);
    const float sy = (float)Hc / (float)(Hc - 1);

    int xc0, xc1, xl0, xl1, xr0, xr1, yc0, yc1, yt0, yt1, yb0, yb1;
    float wxc0, wxc1, wxl0, wxl1, wxr0, wxr1, wyc0, wyc1, wyt0, wyt1, wyb0, wyb1;
    axis_decomp(ix,      Wc, xc0, xc1, wxc0, wxc1);
    axis_decomp(ix - sx, Wc, xl0, xl1, wxl0, wxl1);
    axis_decomp(ix + sx, Wc, xr0, xr1, wxr0, wxr1);
    axis_decomp(iy,      Hc, yc0, yc1, wyc0, wyc1);
    axis_decomp(iy - sy, Hc, yt0, yt1, wyt0, wyt1);
    axis_decomp(iy + sy, Hc, yb0, yb1, wyb0, wyb1);

    const float* base = fm + (size_t)bvc * HWc;
    const float fc = bilin(base, xc0, xc1, wxc0, wxc1, yc0, yc1, wyc0, wyc1);
    const float fl = bilin(base, xl0, xl1, wxl0, wxl1, yc0, yc1, wyc0, wyc1);
    const float fr = bilin(base, xr0, xr1, wxr0, wxr1, yc0, yc1, wyc0, wyc1);
    const float ft = bilin(base, xc0, xc1, wxc0, wxc1, yt0, yt1, wyt0, wyt1);
    const float fb = bilin(base, xc0, xc1, wxc0, wxc1, yb0, yb1, wyb0, wyb1);

    const size_t out_idx = (size_t)blockIdx.x * 256 + threadIdx.x;
    out_f[out_idx] = fc;
    *reinterpret_cast<float2*>(out_g + out_idx * 2) =
        make_float2(0.5f * (fr - fl), 0.5f * (fb - ft));
}

}  // namespace

extern "C" void kernel_launch(void* const* d_in, const int* in_sizes, int n_in,
                              void* d_out, int out_size, void* d_ws, size_t ws_size,
                              hipStream_t stream) {
    const float* fm  = (const float*)d_in[0];
    const float* pts = (const float*)d_in[1];
    const float* K   = (const float*)d_in[2];
    const float* E   = (const float*)d_in[3];
    float* out_f = (float*)d_out;
    float* out_g = out_f + (size_t)BVc * Cc * Nc;

    if (ws_size >= WS_NEED) {
        char* ws = (char*)d_ws;
        float*    fmt      = (float*)(ws + OFF_FMT);
        float*    temp     = (float*)(ws + OFF_TEMP);
        int*      idx      = (int*)(ws + OFF_IDX);
        int*      rank     = (int*)(ws + OFF_RANK);
        unsigned* packed   = (unsigned*)(ws + OFF_PACK);
        unsigned* histT    = (unsigned*)(ws + OFF_HIST);
        unsigned* offT     = (unsigned*)(ws + OFF_OFFT);
        unsigned* totals   = (unsigned*)(ws + OFF_TOT);
        unsigned* bin_base = (unsigned*)(ws + OFF_BASE);

        hist_kernel<<<BVc * NBLK, 256, 0, stream>>>(pts, K, E, histT, packed);
        scan_kernel<<<BVc * NBIN, NBLK, 0, stream>>>(histT, offT, totals);
        base_kernel<<<1, 64, 0, stream>>>(totals, bin_base);
        scatter2_kernel<<<BVc * NBLK, 256, 0, stream>>>(packed, offT, bin_base, idx, rank);

        for (int g = 0; g < BVc; g += CHUNK) {
            const int cs = min(CHUNK, BVc - g);
            transpose_kernel<<<cs * (HWc / 256), 256, 0, stream>>>(fm, fmt, g);
            gather_sorted_kernel<<<cs * (Nc / 256), 256, 0, stream>>>(
                fmt, pts, K, E, idx, temp, g);
            unpermute_kernel<<<cs * (Nc / 256), 256, 0, stream>>>(
                temp, rank, out_f, out_g, g);
        }
    } else {
        fgf_fallback_kernel<<<BVc * Cc * (Nc / 256), 256, 0, stream>>>(
            fm, pts, K, E, out_f, out_g);
    }
}

// Round 7
// 744.743 us; speedup vs baseline: 1.4351x; 1.0994x over previous
//
#include <hip/hip_runtime.h>

// FeatureGradFetcher: B=2 V=5 C=16 H=512 W=640 N=131072
// out = concat(f (B,V,C,N), f_grad (B,V,C,N,2)) flat, float32.
//
// R7 (resubmit after infra failure): 4-threads-per-point gather
// (L1 request-rate fix).
//  - R6 evidence: sorted gather works (818us total) but gather still ~400us
//    aggregate vs ~30us streaming equivalent. Each thread did 20 taps x 4
//    dwordx4 = 80 scattered loads; each wave-instr touched 64 distinct 64B
//    lines -> ~105M line-requests, TA/TCP-serialized at ~1 req/cy/CU.
//  - Fix: 4 lanes per point, one 4-channel float4 each. Each tap = 1 dwordx4
//    per lane; 4 lanes share a line -> 16 line-requests/wave-instr, 26M total
//    (4x fewer). Gather LDS staging dropped: lane cg stores f float4 +
//    contiguous gx/gy float8 directly (temp layout unchanged).
//  - Sort (hist/scan/base/scatter2), transpose, unpermute: unchanged from R6.

namespace {
constexpr int Bc = 2, Vc = 5, Cc = 16, Hc = 512, Wc = 640;
constexpr int Nc = 131072;
constexpr int BVc = Bc * Vc;
constexpr int HWc = Hc * Wc;
constexpr int CHUNK = 4;           // bv planes per pipeline stage
constexpr int NBIN = 128;          // y-bins (4 rows each)
constexpr int NBLK = Nc / 256;     // 512 point-blocks per bv

constexpr size_t FMT_CH   = (size_t)CHUNK * HWc * Cc * sizeof(float);   //  83,886,080
constexpr size_t TEMP_CH  = (size_t)CHUNK * Nc * 48 * sizeof(float);    // 100,663,296
constexpr size_t IDX_B    = (size_t)BVc * Nc * sizeof(int);             //   5,242,880
constexpr size_t HIST_B   = (size_t)BVc * NBIN * NBLK * sizeof(unsigned); // 2,621,440
constexpr size_t TOT_B    = (size_t)BVc * NBIN * sizeof(unsigned);      //       5,120
constexpr size_t OFF_FMT   = 0;
constexpr size_t OFF_TEMP  = OFF_FMT + FMT_CH;
constexpr size_t OFF_IDX   = OFF_TEMP + TEMP_CH;
constexpr size_t OFF_RANK  = OFF_IDX + IDX_B;
constexpr size_t OFF_PACK  = OFF_RANK + IDX_B;
constexpr size_t OFF_HIST  = OFF_PACK + IDX_B;
constexpr size_t OFF_OFFT  = OFF_HIST + HIST_B;
constexpr size_t OFF_TOT   = OFF_OFFT + HIST_B;
constexpr size_t OFF_BASE  = OFF_TOT + TOT_B;
constexpr size_t WS_NEED   = OFF_BASE + TOT_B;   // ~205.5 MB (ws proven >= 209.7 MB)

typedef float f32x2 __attribute__((ext_vector_type(2)));
typedef float f32x4 __attribute__((ext_vector_type(4)));

__device__ __forceinline__ void axis_decomp(float t, int limit,
                                            int& i0, int& i1,
                                            float& w0, float& w1) {
    float f0 = floorf(t);
    float fr = t - f0;
    float f1 = f0 + 1.0f;
    float lim = (float)(limit - 1);
    w0 = (1.0f - fr) * ((f0 >= 0.0f && f0 <= lim) ? 1.0f : 0.0f);
    w1 = fr * ((f1 >= 0.0f && f1 <= lim) ? 1.0f : 0.0f);
    int i = (int)f0;
    i0 = min(max(i, 0), limit - 1);
    i1 = min(max(i + 1, 0), limit - 1);
}

__device__ __forceinline__ void project(const float* __restrict__ pts,
                                        const float* __restrict__ Kmat,
                                        const float* __restrict__ Emat,
                                        int bv, int n, float& ix, float& iy) {
    const int b = bv / Vc;
    const float px = pts[(b * 3 + 0) * Nc + n];
    const float py = pts[(b * 3 + 1) * Nc + n];
    const float pz = pts[(b * 3 + 2) * Nc + n];
    const float* E = Emat + bv * 12;
    const float xx = E[0] * px + E[1] * py + E[2]  * pz + E[3];
    const float yy = E[4] * px + E[5] * py + E[6]  * pz + E[7];
    const float zz = E[8] * px + E[9] * py + E[10] * pz + E[11];
    const float* K = Kmat + bv * 9;
    const float inv_z = 1.0f / zz;
    const float nx = xx * inv_z;
    const float ny = yy * inv_z;
    const float u = K[0] * nx + K[1] * ny + K[2];
    const float v = K[3] * nx + K[4] * ny + K[5];
    const float gx = (u - 0.5f) * (2.0f / (float)(Wc - 1)) - 1.0f;
    const float gy = (v - 0.5f) * (2.0f / (float)(Hc - 1)) - 1.0f;
    ix = ((gx + 1.0f) * (float)Wc - 1.0f) * 0.5f;
    iy = ((gy + 1.0f) * (float)Hc - 1.0f) * 0.5f;
}

// ---- sort step 1: per-block LDS histogram + packed (bin,lrank) ----
__global__ __launch_bounds__(256) void hist_kernel(
    const float* __restrict__ pts, const float* __restrict__ Kmat,
    const float* __restrict__ Emat,
    unsigned* __restrict__ histT,    // (BVc*NBIN) rows x NBLK cols
    unsigned* __restrict__ packed) { // (BVc, Nc): bin<<16 | lrank
    __shared__ unsigned lh[NBIN];
    const int t = (int)threadIdx.x;
    const int blk = (int)blockIdx.x & (NBLK - 1);
    const int bv = (int)blockIdx.x >> 9;
    const int n = (blk << 8) | t;
    if (t < NBIN) lh[t] = 0u;
    __syncthreads();
    float ix, iy;
    project(pts, Kmat, Emat, bv, n, ix, iy);
    const int y0 = min(max((int)floorf(iy), 0), Hc - 1);
    const unsigned bin = (unsigned)(y0 >> 2);  // 4 rows per bin
    const unsigned lrank = atomicAdd(&lh[bin], 1u);  // LDS atomic: no chains
    packed[bv * Nc + n] = (bin << 16) | lrank;
    __syncthreads();
    if (t < NBIN) histT[(size_t)((bv * NBIN) + t) * NBLK + blk] = lh[t];
}

// ---- sort step 2: exclusive scan over blocks, per (bv,bin) row ----
__global__ __launch_bounds__(512) void scan_kernel(
    const unsigned* __restrict__ histT, unsigned* __restrict__ offT,
    unsigned* __restrict__ totals) {
    __shared__ unsigned s[NBLK];
    const int row = (int)blockIdx.x;   // bv*NBIN + bin
    const int t = (int)threadIdx.x;    // blk
    const unsigned own = histT[(size_t)row * NBLK + t];
    s[t] = own;
    __syncthreads();
#pragma unroll
    for (int off = 1; off < NBLK; off <<= 1) {
        const unsigned v = (t >= off) ? s[t - off] : 0u;
        __syncthreads();
        s[t] += v;
        __syncthreads();
    }
    offT[(size_t)row * NBLK + t] = s[t] - own;
    if (t == NBLK - 1) totals[row] = s[t];
}

// ---- sort step 3: per-bv prefix over bins ----
__global__ void base_kernel(const unsigned* __restrict__ totals,
                            unsigned* __restrict__ bin_base) {
    const int bv = (int)threadIdx.x;
    if (bv < BVc) {
        unsigned s = 0;
        for (int b2 = 0; b2 < NBIN; ++b2) {
            bin_base[bv * NBIN + b2] = s;
            s += totals[bv * NBIN + b2];
        }
    }
}

// ---- sort step 4: scatter by computed position (no atomics) ----
__global__ __launch_bounds__(256) void scatter2_kernel(
    const unsigned* __restrict__ packed, const unsigned* __restrict__ offT,
    const unsigned* __restrict__ bin_base,
    int* __restrict__ idx, int* __restrict__ rank) {
    const int t = (int)threadIdx.x;
    const int blk = (int)blockIdx.x & (NBLK - 1);
    const int bv = (int)blockIdx.x >> 9;
    const int n = (blk << 8) | t;
    const unsigned p = packed[bv * Nc + n];
    const unsigned bin = p >> 16;
    const unsigned lrank = p & 0xFFFFu;
    const int row = bv * NBIN + (int)bin;
    const unsigned pos = bin_base[row] + offT[(size_t)row * NBLK + blk] + lrank;
    idx[bv * Nc + (int)pos] = n;
    rank[bv * Nc + n] = (int)pos;
}

// ---- fm (BV,C,H,W) -> fmt chunk (bvl,H,W,C) ----
__global__ __launch_bounds__(256) void transpose_kernel(
    const float* __restrict__ fm, float* __restrict__ fmt, int bv_base) {
    __shared__ float lds[16 * 256];
    const int blocks_per_bv = HWc / 256;  // 1280
    const int bvl = (int)blockIdx.x / blocks_per_bv;
    const int bv = bv_base + bvl;
    const int pix0 = ((int)blockIdx.x % blocks_per_bv) * 256;
    const int t = (int)threadIdx.x;
#pragma unroll
    for (int i = 0; i < 4; ++i) {
        const int l = i * 256 + t;   // float4 slot 0..1023
        const int c = l >> 6;        // channel 0..15
        const int m = l & 63;        // float4 within the 256-px channel row
        const float4 v = *reinterpret_cast<const float4*>(
            fm + (size_t)(bv * 16 + c) * HWc + pix0 + 4 * m);
        *reinterpret_cast<float4*>(&lds[c * 256 + 4 * m]) = v;
    }
    __syncthreads();
    float4* dst = reinterpret_cast<float4*>(fmt + (size_t)(bvl * HWc + pix0) * 16);
#pragma unroll
    for (int j = 0; j < 4; ++j) {
        const int q = j * 256 + t;
        const int p = q >> 2;
        const int k = q & 3;
        float4 v;
        v.x = lds[(4 * k + 0) * 256 + p];
        v.y = lds[(4 * k + 1) * 256 + p];
        v.z = lds[(4 * k + 2) * 256 + p];
        v.w = lds[(4 * k + 3) * 256 + p];
        dst[q] = v;
    }
}

// ---- sorted gather, 4 lanes per point ----
// Block: 256 threads = 64 points x 4 channel-groups. Blocks-per-bvl = N/64 =
// 2048; XCD-affine remap j = (B%8)*256 + B/8 so XCD k owns a contiguous
// sorted slice (~64 rows, ~2.6MB <= 4MB L2).
__global__ __launch_bounds__(256) void gather_sorted_kernel(
    const float* __restrict__ fmt,   // chunk (bvl, H, W, C)
    const float* __restrict__ pts,
    const float* __restrict__ Kmat,
    const float* __restrict__ Emat,
    const int* __restrict__ idx,     // (BV, N) pos -> n
    float* __restrict__ temp,        // chunk (bvl, N, 48)
    int bv_base) {
    const int t = (int)threadIdx.x;
    const int cg = t & 3;            // channel group: channels 4cg..4cg+3
    const int bvl = (int)blockIdx.x >> 11;
    const int B = (int)blockIdx.x & 2047;
    const int j = ((B & 7) << 8) | (B >> 3);   // XCD-affine bijective remap
    const int pos = (j << 6) | (t >> 2);
    const int bv = bv_base + bvl;
    const int n = idx[bv * Nc + pos];
    const int b = bv / Vc;

    const float px = pts[(b * 3 + 0) * Nc + n];
    const float py = pts[(b * 3 + 1) * Nc + n];
    const float pz = pts[(b * 3 + 2) * Nc + n];
    const float* E = Emat + bv * 12;
    const float xx = E[0] * px + E[1] * py + E[2]  * pz + E[3];
    const float yy = E[4] * px + E[5] * py + E[6]  * pz + E[7];
    const float zz = E[8] * px + E[9] * py + E[10] * pz + E[11];
    const float* K = Kmat + bv * 9;
    const float inv_z = 1.0f / zz;
    const float nx = xx * inv_z;
    const float ny = yy * inv_z;
    const float u = K[0] * nx + K[1] * ny + K[2];
    const float v = K[3] * nx + K[4] * ny + K[5];
    const float gx = (u - 0.5f) * (2.0f / (float)(Wc - 1)) - 1.0f;
    const float gy = (v - 0.5f) * (2.0f / (float)(Hc - 1)) - 1.0f;
    const float ix = ((gx + 1.0f) * (float)Wc - 1.0f) * 0.5f;
    const float iy = ((gy + 1.0f) * (float)Hc - 1.0f) * 0.5f;
    const float sx = (float)Wc / (float)(Wc - 1);
    const float sy = (float)Hc / (float)(Hc - 1);

    int xc0, xc1, xl0, xl1, xr0, xr1;
    int yc0, yc1, yt0, yt1, yb0, yb1;
    float wxc0, wxc1, wxl0, wxl1, wxr0, wxr1;
    float wyc0, wyc1, wyt0, wyt1, wyb0, wyb1;
    axis_decomp(ix,      Wc, xc0, xc1, wxc0, wxc1);
    axis_decomp(ix - sx, Wc, xl0, xl1, wxl0, wxl1);
    axis_decomp(ix + sx, Wc, xr0, xr1, wxr0, wxr1);
    axis_decomp(iy,      Hc, yc0, yc1, wyc0, wyc1);
    axis_decomp(iy - sy, Hc, yt0, yt1, wyt0, wyt1);
    axis_decomp(iy + sy, Hc, yb0, yb1, wyb0, wyb1);

    float4 accF  = make_float4(0.f, 0.f, 0.f, 0.f);
    float4 accGx = make_float4(0.f, 0.f, 0.f, 0.f);
    float4 accGy = make_float4(0.f, 0.f, 0.f, 0.f);

    const float* plane = fmt + (size_t)bvl * HWc * 16 + 4 * cg;

    auto tap = [&](int x, int y, float w, float4& acc) {
        const float4 vv = *reinterpret_cast<const float4*>(
            plane + (size_t)(y * Wc + x) * 16);
        acc.x += w * vv.x;
        acc.y += w * vv.y;
        acc.z += w * vv.z;
        acc.w += w * vv.w;
    };
    auto sample = [&](int x0, int x1, float wx0, float wx1,
                      int y0, int y1, float wy0, float wy1,
                      float4& acc, float s) {
        tap(x0, y0, s * wx0 * wy0, acc);
        tap(x1, y0, s * wx1 * wy0, acc);
        tap(x0, y1, s * wx0 * wy1, acc);
        tap(x1, y1, s * wx1 * wy1, acc);
    };

    sample(xc0, xc1, wxc0, wxc1, yc0, yc1, wyc0, wyc1, accF,  1.0f);
    sample(xl0, xl1, wxl0, wxl1, yc0, yc1, wyc0, wyc1, accGx, -0.5f);
    sample(xr0, xr1, wxr0, wxr1, yc0, yc1, wyc0, wyc1, accGx,  0.5f);
    sample(xc0, xc1, wxc0, wxc1, yt0, yt1, wyt0, wyt1, accGy, -0.5f);
    sample(xc0, xc1, wxc0, wxc1, yb0, yb1, wyb0, wyb1, accGy,  0.5f);

    // temp[pos][48]: comps 0..15 = f by channel, 16+2c = gx, 17+2c = gy.
    // Lane cg owns channels 4cg..4cg+3: f float4 at +4cg; gx/gy interleaved
    // pairs form one contiguous float8 at +16+8cg. All 64B lines of the
    // 192B record are fully written by the point's 4 lanes.
    float* rec = temp + (size_t)(bvl * Nc + pos) * 48;
    f32x4 fv = {accF.x, accF.y, accF.z, accF.w};
    __builtin_nontemporal_store(fv, reinterpret_cast<f32x4*>(rec + 4 * cg));
    f32x4 g0 = {accGx.x, accGy.x, accGx.y, accGy.y};
    f32x4 g1 = {accGx.z, accGy.z, accGx.w, accGy.w};
    __builtin_nontemporal_store(g0, reinterpret_cast<f32x4*>(rec + 16 + 8 * cg));
    __builtin_nontemporal_store(g1, reinterpret_cast<f32x4*>(rec + 20 + 8 * cg));
}

// ---- unpermute: out[n] <- temp[rank[n]], LDS transpose to c-major ----
__global__ __launch_bounds__(256) void unpermute_kernel(
    const float* __restrict__ temp, const int* __restrict__ rank,
    float* __restrict__ out_f, float* __restrict__ out_g, int bv_base) {
    __shared__ float lds[48 * 260];
    const int t = (int)threadIdx.x;
    const int bvl = (int)blockIdx.x >> 9;
    const int n0 = ((int)blockIdx.x & 511) << 8;
    const int bv = bv_base + bvl;
    const int n = n0 + t;
    const int pos = rank[bv * Nc + n];
    const f32x4* t4 = reinterpret_cast<const f32x4*>(temp) + (size_t)(bvl * Nc + pos) * 12;
#pragma unroll
    for (int q = 0; q < 12; ++q) {
        f32x4 v = __builtin_nontemporal_load(t4 + q);
        lds[(4 * q + 0) * 260 + t] = v.x;
        lds[(4 * q + 1) * 260 + t] = v.y;
        lds[(4 * q + 2) * 260 + t] = v.z;
        lds[(4 * q + 3) * 260 + t] = v.w;
    }
    __syncthreads();
#pragma unroll
    for (int c = 0; c < 16; ++c) {
        __builtin_nontemporal_store(lds[c * 260 + t],
                                    out_f + (size_t)(bv * 16 + c) * Nc + n);
        f32x2 g2 = {lds[(16 + 2 * c) * 260 + t], lds[(17 + 2 * c) * 260 + t]};
        __builtin_nontemporal_store(g2, reinterpret_cast<f32x2*>(out_g) +
                                            (size_t)(bv * 16 + c) * Nc + n);
    }
}

// ---- fallback (thread per (bv,c,n), direct from (BV,C,H,W)) ----
__device__ __forceinline__ float bilin(const float* __restrict__ base,
                                       int x0, int x1, float wx0, float wx1,
                                       int y0, int y1, float wy0, float wy1) {
    const float* r0 = base + y0 * Wc;
    const float* r1 = base + y1 * Wc;
    return wy0 * (wx0 * r0[x0] + wx1 * r0[x1]) +
           wy1 * (wx0 * r1[x0] + wx1 * r1[x1]);
}

__global__ __launch_bounds__(256) void fgf_fallback_kernel(
    const float* __restrict__ fm, const float* __restrict__ pts,
    const float* __restrict__ Kmat, const float* __restrict__ Emat,
    float* __restrict__ out_f, float* __restrict__ out_g) {
    const int n   = (((int)blockIdx.x & 511) << 8) | (int)threadIdx.x;
    const int bvc = (int)blockIdx.x >> 9;
    const int bv  = bvc >> 4;
    float ix, iy;
    project(pts, Kmat, Emat, bv, n, ix, iy);
    const float sx = (float)Wc / (float)(Wc - 1);
    const float sy = (float)Hc / (float)(Hc - 1);

    int xc0, xc1, xl0, xl1, xr0, xr1, yc0, yc1, yt0, yt1, yb0, yb1;
    float wxc0, wxc1, wxl0, wxl1, wxr0, wxr1, wyc0, wyc1, wyt0, wyt1, wyb0, wyb1;
    axis_decomp(ix,      Wc, xc0, xc1, wxc0, wxc1);
    axis_decomp(ix - sx, Wc, xl0, xl1, wxl0, wxl1);
    axis_decomp(ix + sx, Wc, xr0, xr1, wxr0, wxr1);
    axis_decomp(iy,      Hc, yc0, yc1, wyc0, wyc1);
    axis_decomp(iy - sy, Hc, yt0, yt1, wyt0, wyt1);
    axis_decomp(iy + sy, Hc, yb0, yb1, wyb0, wyb1);

    const float* base = fm + (size_t)bvc * HWc;
    const float fc = bilin(base, xc0, xc1, wxc0, wxc1, yc0, yc1, wyc0, wyc1);
    const float fl = bilin(base, xl0, xl1, wxl0, wxl1, yc0, yc1, wyc0, wyc1);
    const float fr = bilin(base, xr0, xr1, wxr0, wxr1, yc0, yc1, wyc0, wyc1);
    const float ft = bilin(base, xc0, xc1, wxc0, wxc1, yt0, yt1, wyt0, wyt1);
    const float fb = bilin(base, xc0, xc1, wxc0, wxc1, yb0, yb1, wyb0, wyb1);

    const size_t out_idx = (size_t)blockIdx.x * 256 + threadIdx.x;
    out_f[out_idx] = fc;
    *reinterpret_cast<float2*>(out_g + out_idx * 2) =
        make_float2(0.5f * (fr - fl), 0.5f * (fb - ft));
}

}  // namespace

extern "C" void kernel_launch(void* const* d_in, const int* in_sizes, int n_in,
                              void* d_out, int out_size, void* d_ws, size_t ws_size,
                              hipStream_t stream) {
    const float* fm  = (const float*)d_in[0];
    const float* pts = (const float*)d_in[1];
    const float* K   = (const float*)d_in[2];
    const float* E   = (const float*)d_in[3];
    float* out_f = (float*)d_out;
    float* out_g = out_f + (size_t)BVc * Cc * Nc;

    if (ws_size >= WS_NEED) {
        char* ws = (char*)d_ws;
        float*    fmt      = (float*)(ws + OFF_FMT);
        float*    temp     = (float*)(ws + OFF_TEMP);
        int*      idx      = (int*)(ws + OFF_IDX);
        int*      rank     = (int*)(ws + OFF_RANK);
        unsigned* packed   = (unsigned*)(ws + OFF_PACK);
        unsigned* histT    = (unsigned*)(ws + OFF_HIST);
        unsigned* offT     = (unsigned*)(ws + OFF_OFFT);
        unsigned* totals   = (unsigned*)(ws + OFF_TOT);
        unsigned* bin_base = (unsigned*)(ws + OFF_BASE);

        hist_kernel<<<BVc * NBLK, 256, 0, stream>>>(pts, K, E, histT, packed);
        scan_kernel<<<BVc * NBIN, NBLK, 0, stream>>>(histT, offT, totals);
        base_kernel<<<1, 64, 0, stream>>>(totals, bin_base);
        scatter2_kernel<<<BVc * NBLK, 256, 0, stream>>>(packed, offT, bin_base, idx, rank);

        for (int g = 0; g < BVc; g += CHUNK) {
            const int cs = min(CHUNK, BVc - g);
            transpose_kernel<<<cs * (HWc / 256), 256, 0, stream>>>(fm, fmt, g);
            gather_sorted_kernel<<<cs * (Nc / 64), 256, 0, stream>>>(
                fmt, pts, K, E, idx, temp, g);
            unpermute_kernel<<<cs * (Nc / 256), 256, 0, stream>>>(
                temp, rank, out_f, out_g, g);
        }
    } else {
        fgf_fallback_kernel<<<BVc * Cc * (Nc / 256), 256, 0, stream>>>(
            fm, pts, K, E, out_f, out_g);
    }
}